// Round 1
// baseline (1118.630 us; speedup 1.0000x reference)
//
#include <hip/hip_runtime.h>
#include <cstdint>
#include <cstddef>

#define E_EXP 8
#define LDIM 1024
#define ODIM 1024
#define BM 128
#define BN 128
#define BK 32
#define NKSTEP (LDIM / BK)
#define MAXRT 520  // max total row tiles: 65536/128 + 8 ceil-slack

typedef __bf16 bf16x8 __attribute__((ext_vector_type(8)));
typedef float f32x4 __attribute__((ext_vector_type(4)));

__device__ __forceinline__ unsigned short f2bf(float f) {
  uint32_t u = __float_as_uint(f);
  u += 0x7FFFu + ((u >> 16) & 1u);   // round-to-nearest-even
  return (unsigned short)(u >> 16);
}

__device__ __forceinline__ void gload_lds16(const void* g, void* l) {
  __builtin_amdgcn_global_load_lds(
      (const __attribute__((address_space(1))) unsigned int*)g,
      (__attribute__((address_space(3))) unsigned int*)l, 16, 0, 0);
}

// ---------------- routing + x->bf16 conversion (fused) ----------------
__global__ __launch_bounds__(256) void route_kernel(
    const float* __restrict__ x, const float* __restrict__ gate,
    unsigned short* __restrict__ xb, int* __restrict__ cnt,
    int* __restrict__ tokList, float* __restrict__ wList, int T)
{
  const int wid = threadIdx.x >> 6, lane = threadIdx.x & 63;
  const int tok = blockIdx.x * 4 + wid;
  if (tok >= T) return;
  const float* xr = x + (size_t)tok * LDIM;
  unsigned short* xbr = xb + (size_t)tok * LDIM;

  float acc[E_EXP];
#pragma unroll
  for (int e = 0; e < E_EXP; ++e) acc[e] = 0.f;

#pragma unroll
  for (int it = 0; it < 4; ++it) {
    const int c = it * 256 + lane * 4;
    float4 xv = *(const float4*)(xr + c);
    ushort4 bvv;
    bvv.x = f2bf(xv.x); bvv.y = f2bf(xv.y); bvv.z = f2bf(xv.z); bvv.w = f2bf(xv.w);
    *(ushort4*)(xbr + c) = bvv;
#pragma unroll
    for (int e = 0; e < E_EXP; ++e) {
      float4 gv = *(const float4*)(gate + e * LDIM + c);
      acc[e] += xv.x * gv.x + xv.y * gv.y + xv.z * gv.z + xv.w * gv.w;
    }
  }
  // butterfly reduce across 64 lanes
#pragma unroll
  for (int off = 32; off >= 1; off >>= 1) {
#pragma unroll
    for (int e = 0; e < E_EXP; ++e) acc[e] += __shfl_xor(acc[e], off, 64);
  }
  if (lane == 0) {
    int i1 = 0; float m1 = acc[0];
#pragma unroll
    for (int e = 1; e < E_EXP; ++e) if (acc[e] > m1) { m1 = acc[e]; i1 = e; }
    int i2 = -1; float m2 = -1e30f;
#pragma unroll
    for (int e = 0; e < E_EXP; ++e) if (e != i1 && acc[e] > m2) { m2 = acc[e]; i2 = e; }
    float s = 0.f;
#pragma unroll
    for (int e = 0; e < E_EXP; ++e) s += __expf(acc[e] - m1);
    const float inv = 1.f / s;
    const float w1 = inv;                    // exp(0)/s
    const float w2 = __expf(m2 - m1) * inv;
    int p1 = atomicAdd(&cnt[i1], 1);
    tokList[(size_t)i1 * T + p1] = tok; wList[(size_t)i1 * T + p1] = w1;
    int p2 = atomicAdd(&cnt[i2], 1);
    tokList[(size_t)i2 * T + p2] = tok; wList[(size_t)i2 * T + p2] = w2;
  }
}

// ---------------- expert_w -> bf16 ----------------
__global__ __launch_bounds__(256) void convw_kernel(
    const float* __restrict__ w, unsigned short* __restrict__ wb, int n4)
{
  int i = blockIdx.x * 256 + threadIdx.x;
  if (i >= n4) return;
  float4 v = *(const float4*)(w + (size_t)i * 4);
  ushort4 b;
  b.x = f2bf(v.x); b.y = f2bf(v.y); b.z = f2bf(v.z); b.w = f2bf(v.w);
  *(ushort4*)(wb + (size_t)i * 4) = b;
}

// ---------------- row-tile prefix sums ----------------
__global__ void finalize_kernel(const int* __restrict__ cnt, int* __restrict__ prefix)
{
  if (threadIdx.x == 0 && blockIdx.x == 0) {
    int s = 0; prefix[0] = 0;
    for (int e = 0; e < E_EXP; ++e) { s += (cnt[e] + BM - 1) / BM; prefix[e + 1] = s; }
  }
}

// ---------------- grouped gathered GEMM, bf16 MFMA ----------------
__global__ __launch_bounds__(256) void moe_gemm(
    const unsigned short* __restrict__ xb, const unsigned short* __restrict__ wb,
    const float* __restrict__ bias, const int* __restrict__ cnt,
    const int* __restrict__ prefix, const int* __restrict__ tokList,
    const float* __restrict__ wList, float* __restrict__ out, int T)
{
  __shared__ __align__(16) unsigned short lds[2][2][BM * BK];
  const int tid = threadIdx.x;
  const int lane = tid & 63, wid = tid >> 6;
  const int wm = wid >> 1, wn = wid & 1;

  const int totalRow = prefix[E_EXP];
  // XCD-chunked bijective swizzle over fixed 4160-block grid (8 * 520)
  const int swz = ((int)blockIdx.x & 7) * MAXRT + ((int)blockIdx.x >> 3);
  if (swz >= totalRow * 8) return;
  const int rowTileG = swz >> 3, colTile = swz & 7;
  int e = 0;
#pragma unroll
  for (int k = 0; k < E_EXP - 1; ++k) e += (rowTileG >= prefix[k + 1]) ? 1 : 0;
  const int rtLocal = rowTileG - prefix[e];
  const int ce = cnt[e];
  const int rowBase = rtLocal * BM;
  const int* tokL = tokList + (size_t)e * T;
  const float* wgtL = wList + (size_t)e * T;

  // staging: thread covers chunk (tid&3) of rows (tid>>2) and 64+(tid>>2)
  const int rr = tid >> 2, chunk = tid & 3;
  int ti0 = rowBase + rr;       if (ti0 >= ce) ti0 = ce - 1;
  int ti1 = rowBase + 64 + rr;  if (ti1 >= ce) ti1 = ce - 1;
  const int tok0 = tokL[ti0], tok1 = tokL[ti1];
  const unsigned short* aS0 = xb + (size_t)tok0 * LDIM + chunk * 8;
  const unsigned short* aS1 = xb + (size_t)tok1 * LDIM + chunk * 8;
  const unsigned short* bS0 = wb + ((size_t)e * ODIM + colTile * BN + rr) * LDIM + chunk * 8;
  const unsigned short* bS1 = bS0 + (size_t)64 * LDIM;

  int aoff[4], boff[4];
#pragma unroll
  for (int m = 0; m < 4; ++m)
    aoff[m] = (wm * 64 + m * 16 + (lane & 15)) * BK + (lane >> 4) * 8;
#pragma unroll
  for (int n = 0; n < 4; ++n)
    boff[n] = (wn * 64 + n * 16 + (lane & 15)) * BK + (lane >> 4) * 8;

  f32x4 acc[4][4] = {};

  auto stage = [&](int b, int k) {
    unsigned short* A = &lds[b][0][0];
    unsigned short* B = &lds[b][1][0];
    gload_lds16(aS0 + k, A + wid * 512);          // bytes: wid*1024
    gload_lds16(aS1 + k, A + 2048 + wid * 512);   // bytes: 4096 + wid*1024
    gload_lds16(bS0 + k, B + wid * 512);
    gload_lds16(bS1 + k, B + 2048 + wid * 512);
  };

  stage(0, 0);
  __syncthreads();

#pragma unroll 1
  for (int ks = 0; ks < NKSTEP; ++ks) {
    const int cur = ks & 1;
    if (ks + 1 < NKSTEP) stage(cur ^ 1, (ks + 1) * BK);
    const unsigned short* As = &lds[cur][0][0];
    const unsigned short* Bs = &lds[cur][1][0];
    bf16x8 af[4], bfv[4];
#pragma unroll
    for (int m = 0; m < 4; ++m) af[m] = *(const bf16x8*)(As + aoff[m]);
#pragma unroll
    for (int n = 0; n < 4; ++n) bfv[n] = *(const bf16x8*)(Bs + boff[n]);
#pragma unroll
    for (int m = 0; m < 4; ++m)
#pragma unroll
      for (int n = 0; n < 4; ++n)
        acc[m][n] = __builtin_amdgcn_mfma_f32_16x16x32_bf16(af[m], bfv[n], acc[m][n], 0, 0, 0);
    __syncthreads();  // drains this step's stage (vmcnt) + all ds_reads (lgkm)
  }

  // epilogue: out[tok, col] += w * (acc + bias[e, col])
  int cols[4]; float bv[4];
#pragma unroll
  for (int n = 0; n < 4; ++n) {
    cols[n] = colTile * BN + wn * 64 + n * 16 + (lane & 15);
    bv[n] = bias[e * ODIM + cols[n]];
  }
#pragma unroll
  for (int m = 0; m < 4; ++m) {
#pragma unroll
    for (int r = 0; r < 4; ++r) {
      const int row = rowBase + wm * 64 + m * 16 + (lane >> 4) * 4 + r;
      if (row < ce) {
        const int tok = tokL[row];
        const float wgt = wgtL[row];
        float* orow = out + (size_t)tok * ODIM;
#pragma unroll
        for (int n = 0; n < 4; ++n)
          unsafeAtomicAdd(&orow[cols[n]], wgt * (acc[m][n][r] + bv[n]));
      }
    }
  }
}

// ---------------- emergency fallback (ws too small): slow but correct ----------------
__global__ __launch_bounds__(256) void naive_moe(
    const float* __restrict__ x, const float* __restrict__ gate,
    const float* __restrict__ ew, const float* __restrict__ eb,
    float* __restrict__ out, int T)
{
  const int tok = blockIdx.x, tid = threadIdx.x;
  __shared__ float xs[LDIM];
  __shared__ float logits[E_EXP];
  __shared__ float sw1, sw2; __shared__ int si1, si2;
  for (int i = tid; i < LDIM; i += 256) xs[i] = x[(size_t)tok * LDIM + i];
  __syncthreads();
  const int wid = tid >> 6, lane = tid & 63;
  for (int e = wid; e < E_EXP; e += 4) {
    float a = 0.f;
    for (int i = lane; i < LDIM; i += 64) a += xs[i] * gate[e * LDIM + i];
    for (int off = 32; off >= 1; off >>= 1) a += __shfl_xor(a, off, 64);
    if (lane == 0) logits[e] = a;
  }
  __syncthreads();
  if (tid == 0) {
    int i1 = 0; float m1 = logits[0];
    for (int e = 1; e < E_EXP; ++e) if (logits[e] > m1) { m1 = logits[e]; i1 = e; }
    int i2 = -1; float m2 = -1e30f;
    for (int e = 0; e < E_EXP; ++e) if (e != i1 && logits[e] > m2) { m2 = logits[e]; i2 = e; }
    float s = 0.f;
    for (int e = 0; e < E_EXP; ++e) s += __expf(logits[e] - m1);
    si1 = i1; si2 = i2; sw1 = 1.f / s; sw2 = __expf(m2 - m1) / s;
  }
  __syncthreads();
  const int i1 = si1, i2 = si2; const float w1 = sw1, w2 = sw2;
  for (int o = tid; o < ODIM; o += 256) {
    float a1 = 0.f, a2 = 0.f;
    const float* p1 = ew + ((size_t)i1 * ODIM + o) * LDIM;
    const float* p2 = ew + ((size_t)i2 * ODIM + o) * LDIM;
    for (int l = 0; l < LDIM; ++l) { a1 += xs[l] * p1[l]; a2 += xs[l] * p2[l]; }
    out[(size_t)tok * ODIM + o] =
        w1 * (a1 + eb[i1 * ODIM + o]) + w2 * (a2 + eb[i2 * ODIM + o]);
  }
}

extern "C" void kernel_launch(void* const* d_in, const int* in_sizes, int n_in,
                              void* d_out, int out_size, void* d_ws, size_t ws_size,
                              hipStream_t stream) {
  const float* x    = (const float*)d_in[0];
  const float* gate = (const float*)d_in[1];
  const float* ew   = (const float*)d_in[2];
  const float* eb   = (const float*)d_in[3];
  float* out = (float*)d_out;
  const int T = in_sizes[0] / LDIM;  // 32768

  // ws layout (256B-aligned regions)
  const size_t offCnt    = 0;                                  // 8 ints
  const size_t offPrefix = 256;                                // 9 ints
  const size_t offTok    = 512;
  const size_t offW      = offTok + (size_t)E_EXP * T * 4;     // 1 MB each
  const size_t offXb     = offW + (size_t)E_EXP * T * 4;
  const size_t offWb     = offXb + (size_t)T * LDIM * 2;       // 64 MB
  const size_t need      = offWb + (size_t)E_EXP * ODIM * LDIM * 2;  // ~86 MB

  if (ws_size < need) {
    naive_moe<<<T, 256, 0, stream>>>(x, gate, ew, eb, out, T);
    return;
  }

  char* ws = (char*)d_ws;
  hipMemsetAsync(ws + offCnt, 0, 64, stream);
  hipMemsetAsync(d_out, 0, (size_t)out_size * 4, stream);

  route_kernel<<<T / 4, 256, 0, stream>>>(
      x, gate, (unsigned short*)(ws + offXb), (int*)(ws + offCnt),
      (int*)(ws + offTok), (float*)(ws + offW), T);

  const int n4 = E_EXP * ODIM * LDIM / 4;
  convw_kernel<<<(n4 + 255) / 256, 256, 0, stream>>>(ew, (unsigned short*)(ws + offWb), n4);

  finalize_kernel<<<1, 64, 0, stream>>>((int*)(ws + offCnt), (int*)(ws + offPrefix));

  moe_gemm<<<8 * MAXRT, 256, 0, stream>>>(
      (const unsigned short*)(ws + offXb), (const unsigned short*)(ws + offWb),
      eb, (const int*)(ws + offCnt), (const int*)(ws + offPrefix),
      (const int*)(ws + offTok), (const float*)(ws + offW), out, T);
}

// Round 2
// 433.901 us; speedup vs baseline: 2.5781x; 2.5781x over previous
//
#include <hip/hip_runtime.h>
#include <cstdint>
#include <cstddef>

#define E_EXP 8
#define LDIM 1024
#define ODIM 1024
#define BM 128
#define BN 128
#define BK 32
#define NKSTEP (LDIM / BK)
#define MAXRT 520  // max total row tiles: 65536/128 + 8 ceil-slack

typedef __bf16 bf16x8 __attribute__((ext_vector_type(8)));
typedef float f32x4 __attribute__((ext_vector_type(4)));

__device__ __forceinline__ unsigned short f2bf(float f) {
  uint32_t u = __float_as_uint(f);
  u += 0x7FFFu + ((u >> 16) & 1u);   // round-to-nearest-even
  return (unsigned short)(u >> 16);
}

__device__ __forceinline__ void gload_lds16(const void* g, void* l) {
  __builtin_amdgcn_global_load_lds(
      (const __attribute__((address_space(1))) unsigned int*)g,
      (__attribute__((address_space(3))) unsigned int*)l, 16, 0, 0);
}

// ---------------- routing + x->bf16 conversion (fused, NO atomics) ----------------
__global__ __launch_bounds__(256) void route_kernel(
    const float* __restrict__ x, const float* __restrict__ gate,
    unsigned short* __restrict__ xb, int* __restrict__ sel,
    float2* __restrict__ pw, int T)
{
  const int wid = threadIdx.x >> 6, lane = threadIdx.x & 63;
  const int tok = blockIdx.x * 4 + wid;
  if (tok >= T) return;
  const float* xr = x + (size_t)tok * LDIM;
  unsigned short* xbr = xb + (size_t)tok * LDIM;

  float acc[E_EXP];
#pragma unroll
  for (int e = 0; e < E_EXP; ++e) acc[e] = 0.f;

#pragma unroll
  for (int it = 0; it < 4; ++it) {
    const int c = it * 256 + lane * 4;
    float4 xv = *(const float4*)(xr + c);
    ushort4 bvv;
    bvv.x = f2bf(xv.x); bvv.y = f2bf(xv.y); bvv.z = f2bf(xv.z); bvv.w = f2bf(xv.w);
    *(ushort4*)(xbr + c) = bvv;
#pragma unroll
    for (int e = 0; e < E_EXP; ++e) {
      float4 gv = *(const float4*)(gate + e * LDIM + c);
      acc[e] += xv.x * gv.x + xv.y * gv.y + xv.z * gv.z + xv.w * gv.w;
    }
  }
  // butterfly reduce across 64 lanes
#pragma unroll
  for (int off = 32; off >= 1; off >>= 1) {
#pragma unroll
    for (int e = 0; e < E_EXP; ++e) acc[e] += __shfl_xor(acc[e], off, 64);
  }
  if (lane == 0) {
    int i1 = 0; float m1 = acc[0];
#pragma unroll
    for (int e = 1; e < E_EXP; ++e) if (acc[e] > m1) { m1 = acc[e]; i1 = e; }
    int i2 = -1; float m2 = -1e30f;
#pragma unroll
    for (int e = 0; e < E_EXP; ++e) if (e != i1 && acc[e] > m2) { m2 = acc[e]; i2 = e; }
    float s = 0.f;
#pragma unroll
    for (int e = 0; e < E_EXP; ++e) s += __expf(acc[e] - m1);
    const float inv = 1.f / s;
    sel[tok] = i1 | (i2 << 4);
    pw[tok] = make_float2(inv, __expf(m2 - m1) * inv);
  }
}

// ---------------- scatter into per-expert lists (block-aggregated atomics) ----
// 2048 tokens per block; LDS histogram + one global atomic per (block, expert).
__global__ __launch_bounds__(256) void build_lists(
    const int* __restrict__ sel, const float2* __restrict__ pw,
    int* __restrict__ cnt, int* __restrict__ tokList, float* __restrict__ wList,
    int T)
{
  __shared__ int lhist[E_EXP];
  __shared__ int lbase[E_EXP];
  const int tid = threadIdx.x;
  if (tid < E_EXP) lhist[tid] = 0;
  __syncthreads();
  const int t0 = blockIdx.x * 2048;

  int mtok[8], msel[8]; float2 mw[8]; int sA[8], sB[8]; bool val[8];
#pragma unroll
  for (int i = 0; i < 8; ++i) {
    const int t = t0 + i * 256 + tid;
    val[i] = (t < T);
    mtok[i] = t;
    int s = 0; float2 w = make_float2(0.f, 0.f);
    if (val[i]) { s = sel[t]; w = pw[t]; }
    msel[i] = s; mw[i] = w;
    if (val[i]) {
      sA[i] = atomicAdd(&lhist[s & 15], 1);
      sB[i] = atomicAdd(&lhist[(s >> 4) & 15], 1);
    }
  }
  __syncthreads();
  if (tid < E_EXP) lbase[tid] = atomicAdd(&cnt[tid], lhist[tid]);
  __syncthreads();
#pragma unroll
  for (int i = 0; i < 8; ++i) {
    if (val[i]) {
      const int e1 = msel[i] & 15, e2 = (msel[i] >> 4) & 15;
      const int p1 = lbase[e1] + sA[i];
      tokList[(size_t)e1 * T + p1] = mtok[i]; wList[(size_t)e1 * T + p1] = mw[i].x;
      const int p2 = lbase[e2] + sB[i];
      tokList[(size_t)e2 * T + p2] = mtok[i]; wList[(size_t)e2 * T + p2] = mw[i].y;
    }
  }
}

// ---------------- expert_w -> bf16 ----------------
__global__ __launch_bounds__(256) void convw_kernel(
    const float* __restrict__ w, unsigned short* __restrict__ wb, int n4)
{
  int i = blockIdx.x * 256 + threadIdx.x;
  if (i >= n4) return;
  float4 v = *(const float4*)(w + (size_t)i * 4);
  ushort4 b;
  b.x = f2bf(v.x); b.y = f2bf(v.y); b.z = f2bf(v.z); b.w = f2bf(v.w);
  *(ushort4*)(wb + (size_t)i * 4) = b;
}

// ---------------- row-tile prefix sums ----------------
__global__ void finalize_kernel(const int* __restrict__ cnt, int* __restrict__ prefix)
{
  if (threadIdx.x == 0 && blockIdx.x == 0) {
    int s = 0; prefix[0] = 0;
    for (int e = 0; e < E_EXP; ++e) { s += (cnt[e] + BM - 1) / BM; prefix[e + 1] = s; }
  }
}

// ---------------- grouped gathered GEMM, bf16 MFMA ----------------
__global__ __launch_bounds__(256) void moe_gemm(
    const unsigned short* __restrict__ xb, const unsigned short* __restrict__ wb,
    const float* __restrict__ bias, const int* __restrict__ cnt,
    const int* __restrict__ prefix, const int* __restrict__ tokList,
    const float* __restrict__ wList, float* __restrict__ out, int T)
{
  __shared__ __align__(16) unsigned short lds[2][2][BM * BK];
  const int tid = threadIdx.x;
  const int lane = tid & 63, wid = tid >> 6;
  const int wm = wid >> 1, wn = wid & 1;

  const int totalRow = prefix[E_EXP];
  // XCD-chunked bijective swizzle over fixed 4160-block grid (8 * 520)
  const int swz = ((int)blockIdx.x & 7) * MAXRT + ((int)blockIdx.x >> 3);
  if (swz >= totalRow * 8) return;
  const int rowTileG = swz >> 3, colTile = swz & 7;
  int e = 0;
#pragma unroll
  for (int k = 0; k < E_EXP - 1; ++k) e += (rowTileG >= prefix[k + 1]) ? 1 : 0;
  const int rtLocal = rowTileG - prefix[e];
  const int ce = cnt[e];
  const int rowBase = rtLocal * BM;
  const int* tokL = tokList + (size_t)e * T;
  const float* wgtL = wList + (size_t)e * T;

  // staging: thread covers chunk (tid&3) of rows (tid>>2) and 64+(tid>>2)
  const int rr = tid >> 2, chunk = tid & 3;
  int ti0 = rowBase + rr;       if (ti0 >= ce) ti0 = ce - 1;
  int ti1 = rowBase + 64 + rr;  if (ti1 >= ce) ti1 = ce - 1;
  const int tok0 = tokL[ti0], tok1 = tokL[ti1];
  const unsigned short* aS0 = xb + (size_t)tok0 * LDIM + chunk * 8;
  const unsigned short* aS1 = xb + (size_t)tok1 * LDIM + chunk * 8;
  const unsigned short* bS0 = wb + ((size_t)e * ODIM + colTile * BN + rr) * LDIM + chunk * 8;
  const unsigned short* bS1 = bS0 + (size_t)64 * LDIM;

  int aoff[4], boff[4];
#pragma unroll
  for (int m = 0; m < 4; ++m)
    aoff[m] = (wm * 64 + m * 16 + (lane & 15)) * BK + (lane >> 4) * 8;
#pragma unroll
  for (int n = 0; n < 4; ++n)
    boff[n] = (wn * 64 + n * 16 + (lane & 15)) * BK + (lane >> 4) * 8;

  f32x4 acc[4][4] = {};

  auto stage = [&](int b, int k) {
    unsigned short* A = &lds[b][0][0];
    unsigned short* B = &lds[b][1][0];
    gload_lds16(aS0 + k, A + wid * 512);          // bytes: wid*1024
    gload_lds16(aS1 + k, A + 2048 + wid * 512);   // bytes: 4096 + wid*1024
    gload_lds16(bS0 + k, B + wid * 512);
    gload_lds16(bS1 + k, B + 2048 + wid * 512);
  };

  stage(0, 0);
  __syncthreads();

#pragma unroll 1
  for (int ks = 0; ks < NKSTEP; ++ks) {
    const int cur = ks & 1;
    if (ks + 1 < NKSTEP) stage(cur ^ 1, (ks + 1) * BK);
    const unsigned short* As = &lds[cur][0][0];
    const unsigned short* Bs = &lds[cur][1][0];
    bf16x8 af[4], bfv[4];
#pragma unroll
    for (int m = 0; m < 4; ++m) af[m] = *(const bf16x8*)(As + aoff[m]);
#pragma unroll
    for (int n = 0; n < 4; ++n) bfv[n] = *(const bf16x8*)(Bs + boff[n]);
#pragma unroll
    for (int m = 0; m < 4; ++m)
#pragma unroll
      for (int n = 0; n < 4; ++n)
        acc[m][n] = __builtin_amdgcn_mfma_f32_16x16x32_bf16(af[m], bfv[n], acc[m][n], 0, 0, 0);
    __syncthreads();  // drains this step's stage (vmcnt) + all ds_reads (lgkm)
  }

  // epilogue: out[tok, col] += w * (acc + bias[e, col])
  int cols[4]; float bv[4];
#pragma unroll
  for (int n = 0; n < 4; ++n) {
    cols[n] = colTile * BN + wn * 64 + n * 16 + (lane & 15);
    bv[n] = bias[e * ODIM + cols[n]];
  }
#pragma unroll
  for (int m = 0; m < 4; ++m) {
#pragma unroll
    for (int r = 0; r < 4; ++r) {
      const int row = rowBase + wm * 64 + m * 16 + (lane >> 4) * 4 + r;
      if (row < ce) {
        const int tok = tokL[row];
        const float wgt = wgtL[row];
        float* orow = out + (size_t)tok * ODIM;
#pragma unroll
        for (int n = 0; n < 4; ++n)
          unsafeAtomicAdd(&orow[cols[n]], wgt * (acc[m][n][r] + bv[n]));
      }
    }
  }
}

// ---------------- emergency fallback (ws too small): slow but correct ----------------
__global__ __launch_bounds__(256) void naive_moe(
    const float* __restrict__ x, const float* __restrict__ gate,
    const float* __restrict__ ew, const float* __restrict__ eb,
    float* __restrict__ out, int T)
{
  const int tok = blockIdx.x, tid = threadIdx.x;
  __shared__ float xs[LDIM];
  __shared__ float logits[E_EXP];
  __shared__ float sw1, sw2; __shared__ int si1, si2;
  for (int i = tid; i < LDIM; i += 256) xs[i] = x[(size_t)tok * LDIM + i];
  __syncthreads();
  const int wid = tid >> 6, lane = tid & 63;
  for (int e = wid; e < E_EXP; e += 4) {
    float a = 0.f;
    for (int i = lane; i < LDIM; i += 64) a += xs[i] * gate[e * LDIM + i];
    for (int off = 32; off >= 1; off >>= 1) a += __shfl_xor(a, off, 64);
    if (lane == 0) logits[e] = a;
  }
  __syncthreads();
  if (tid == 0) {
    int i1 = 0; float m1 = logits[0];
    for (int e = 1; e < E_EXP; ++e) if (logits[e] > m1) { m1 = logits[e]; i1 = e; }
    int i2 = -1; float m2 = -1e30f;
    for (int e = 0; e < E_EXP; ++e) if (e != i1 && logits[e] > m2) { m2 = logits[e]; i2 = e; }
    float s = 0.f;
    for (int e = 0; e < E_EXP; ++e) s += __expf(logits[e] - m1);
    si1 = i1; si2 = i2; sw1 = 1.f / s; sw2 = __expf(m2 - m1) / s;
  }
  __syncthreads();
  const int i1 = si1, i2 = si2; const float w1 = sw1, w2 = sw2;
  for (int o = tid; o < ODIM; o += 256) {
    float a1 = 0.f, a2 = 0.f;
    const float* p1 = ew + ((size_t)i1 * ODIM + o) * LDIM;
    const float* p2 = ew + ((size_t)i2 * ODIM + o) * LDIM;
    for (int l = 0; l < LDIM; ++l) { a1 += xs[l] * p1[l]; a2 += xs[l] * p2[l]; }
    out[(size_t)tok * ODIM + o] =
        w1 * (a1 + eb[i1 * ODIM + o]) + w2 * (a2 + eb[i2 * ODIM + o]);
  }
}

extern "C" void kernel_launch(void* const* d_in, const int* in_sizes, int n_in,
                              void* d_out, int out_size, void* d_ws, size_t ws_size,
                              hipStream_t stream) {
  const float* x    = (const float*)d_in[0];
  const float* gate = (const float*)d_in[1];
  const float* ew   = (const float*)d_in[2];
  const float* eb   = (const float*)d_in[3];
  float* out = (float*)d_out;
  const int T = in_sizes[0] / LDIM;  // 32768

  // ws layout (256B-aligned regions)
  const size_t offCnt    = 0;                                  // 8 ints
  const size_t offPrefix = 256;                                // 9 ints
  const size_t offSel    = 512;                                // T ints
  const size_t offPw     = offSel + (size_t)T * 4;             // T float2
  const size_t offTok    = offPw + (size_t)T * 8;
  const size_t offW      = offTok + (size_t)E_EXP * T * 4;     // 1 MB each
  const size_t offXb     = offW + (size_t)E_EXP * T * 4;
  const size_t offWb     = offXb + (size_t)T * LDIM * 2;       // 64 MB
  const size_t need      = offWb + (size_t)E_EXP * ODIM * LDIM * 2;  // ~86.4 MB

  if (ws_size < need) {
    naive_moe<<<T, 256, 0, stream>>>(x, gate, ew, eb, out, T);
    return;
  }

  char* ws = (char*)d_ws;
  hipMemsetAsync(ws + offCnt, 0, 64, stream);
  hipMemsetAsync(d_out, 0, (size_t)out_size * 4, stream);

  route_kernel<<<T / 4, 256, 0, stream>>>(
      x, gate, (unsigned short*)(ws + offXb), (int*)(ws + offSel),
      (float2*)(ws + offPw), T);

  const int n4 = E_EXP * ODIM * LDIM / 4;
  convw_kernel<<<(n4 + 255) / 256, 256, 0, stream>>>(ew, (unsigned short*)(ws + offWb), n4);

  build_lists<<<(T + 2047) / 2048, 256, 0, stream>>>(
      (const int*)(ws + offSel), (const float2*)(ws + offPw),
      (int*)(ws + offCnt), (int*)(ws + offTok), (float*)(ws + offW), T);

  finalize_kernel<<<1, 64, 0, stream>>>((int*)(ws + offCnt), (int*)(ws + offPrefix));

  moe_gemm<<<8 * MAXRT, 256, 0, stream>>>(
      (const unsigned short*)(ws + offXb), (const unsigned short*)(ws + offWb),
      eb, (const int*)(ws + offCnt), (const int*)(ws + offPrefix),
      (const int*)(ws + offTok), (const float*)(ws + offW), out, T);
}